// Round 20
// baseline (163.038 us; speedup 1.0000x reference)
//
#include <hip/hip_runtime.h>

// Problem constants (from reference)
#define NB    32
#define KJ    17
#define CIN   2048
#define HWSZ  4096     // H*W = 64*64
#define WDIM  64
#define CEMB  2112     // 64 + 2048
#define HID   128
#define NROWS (NB*KJ)  // 544
#define SPLITK 4

// Skeleton adjacency mask (H36M edges + diagonal), row i -> bitmask over j
__device__ __constant__ unsigned c_mask[KJ] = {
  0x00093u, 0x00007u, 0x0000Eu, 0x0000Cu, 0x00031u, 0x00070u, 0x00060u,
  0x00181u, 0x04B80u, 0x00700u, 0x00600u, 0x01900u, 0x03800u, 0x03000u,
  0x0C100u, 0x1C000u, 0x18000u
};

// Sparse neighbor table (excl. diagonal), padded to 4 with non-edge indices
// (A[i][pad] == 0 after masked softmax, so pads contribute exactly 0).
__device__ __constant__ unsigned char c_nbr4[KJ][4] = {
  {1,4,7,2},{0,2,3,3},{1,3,0,0},{2,0,0,0},{0,5,1,1},{4,6,0,0},{5,0,0,0},
  {0,8,1,1},{7,9,11,14},{8,10,0,0},{9,0,0,0},{8,12,0,0},{11,13,0,0},
  {12,0,0,0},{8,15,0,0},{14,16,0,0},{15,0,0,0}
};

// function, not macro: macro param named `w` collides with `.w` member
__device__ __forceinline__ float fma4(const float4 s, const float4 wv, float a) {
  return fmaf(s.x, wv.x, fmaf(s.y, wv.y, fmaf(s.z, wv.z, fmaf(s.w, wv.w, a))));
}

// ---------------------------------------------------------------------------
// K_front: blocks 0..543: heatmap argmax + posemb + OWN-ROW feature gather.
//          blocks 544..1327: weight repack (gather-read, coalesced write).
// ---------------------------------------------------------------------------
__global__ __launch_bounds__(256) void k_front(
    const float* __restrict__ heatmap, const float* __restrict__ bbox,
    const float* __restrict__ pos_w, const float* __restrict__ pos_b,
    const float* __restrict__ Wi, const float* __restrict__ Wh,
    const float* __restrict__ x, float* __restrict__ h_ws,
    float4* __restrict__ Wpi4, float4* __restrict__ Wph4) {
  const int blk = blockIdx.x;
  const int t = threadIdx.x;

  if (blk >= NROWS) {                    // ---- packing blocks ----
    const int pb = blk - NROWS;
    if (pb < 528) {                      // Wpi: 135168 float4
      const int idx4 = pb * 256 + t;
      const int d = idx4 & 127, rest = idx4 >> 7;
      const int c4 = rest % 528, p = rest / 528;
      const float* src = Wi + ((size_t)(p * CEMB + c4 * 4)) * HID + d;
      Wpi4[((size_t)p * 528 + c4) * 128 + d] =
          make_float4(src[0], src[HID], src[2 * HID], src[3 * HID]);
    } else {                             // Wph: 65536 float4
      const int idx4 = (pb - 528) * 256 + t;
      const int d = idx4 & 127, rest = idx4 >> 7;
      const int c4 = rest & 31, lp = rest >> 5;
      const float* src = Wh + ((size_t)(lp * HID + c4 * 4)) * HID + d;
      Wph4[((size_t)lp * 32 + c4) * 128 + d] =
          make_float4(src[0], src[HID], src[2 * HID], src[3 * HID]);
    }
    return;
  }

  // ---- per-(n,k) blocks ----
  const int b = blk;                     // n*17 + k
  const int n = b / KJ;
  __shared__ float svals[256];
  __shared__ int   sidx[256];

  const float4* hm4 = (const float4*)(heatmap + (size_t)b * HWSZ);
  float best = -1e30f; int bidx = 0;
  #pragma unroll
  for (int k = 0; k < 4; ++k) {
    const int vi = k * 256 + t;
    const float4 v = hm4[vi];
    const int base = vi * 4;
    if (v.x > best) { best = v.x; bidx = base;     }
    if (v.y > best) { best = v.y; bidx = base + 1; }
    if (v.z > best) { best = v.z; bidx = base + 2; }
    if (v.w > best) { best = v.w; bidx = base + 3; }
  }
  svals[t] = best; sidx[t] = bidx;
  __syncthreads();
  for (int s = 128; s > 0; s >>= 1) {
    if (t < s) {
      const float v2 = svals[t + s]; const int i2 = sidx[t + s];
      if (v2 > svals[t] || (v2 == svals[t] && i2 < sidx[t])) {
        svals[t] = v2; sidx[t] = i2;
      }
    }
    __syncthreads();
  }
  const int loc = sidx[0];               // valid in all threads

  if (t < 64) {
    const float kx = (float)(loc & (WDIM - 1));
    const float ky = (float)(loc >> 6);
    float in6[6];
    in6[0] = kx * (2.0f / 64.0f) - 1.0f;
    in6[1] = ky * (2.0f / 64.0f) - 1.0f;
    in6[2] = bbox[n * 4 + 0] * (2.0f / 1920.0f) - 1.0f;
    in6[3] = bbox[n * 4 + 1] * (2.0f / 1080.0f) - 1.0f;
    in6[4] = bbox[n * 4 + 2] * (1.0f / 1920.0f);
    in6[5] = bbox[n * 4 + 3] * (1.0f / 1080.0f);
    float acc = pos_b[t];
    #pragma unroll
    for (int c = 0; c < 6; ++c) acc = fmaf(in6[c], pos_w[c * 64 + t], acc);
    h_ws[(size_t)b * CEMB + t] = acc;
  }

  // own-row scattered gather: 8 channels/thread, independent loads
  const float* xn = x + (size_t)n * CIN * HWSZ + loc;
  float* hrow = h_ws + (size_t)b * CEMB + 64;
  #pragma unroll
  for (int k = 0; k < 8; ++k) {
    const int c = k * 256 + t;
    hrow[c] = xn[(size_t)c * HWSZ];
  }
}

// ---------------------------------------------------------------------------
// K_gemm V3: input GEMM  C[544][256] = h[544][2112] @ [Wi0|Wi1], split-K=4
// grid (34, 2, 4), block 256 = 4 rowgroups x 64 colpairs. Each thread:
// 4 rows x 2 adjacent cols -> 8 fma4 per 4 ds_read_b128; W pairwise-contig.
// ---------------------------------------------------------------------------
__global__ __launch_bounds__(256) void k_gemm_in(
    const float* __restrict__ Wpi_f, const float* __restrict__ h_ws,
    float* __restrict__ part) {
  const int bm = blockIdx.x, bn = blockIdx.y, bz = blockIdx.z;
  const int t = threadIdx.x;
  const int jg = t & 63, g = t >> 6;            // colpair, row group (4 rows)
  const int row0 = bm * 16;
  const float4* W4 = (const float4*)Wpi_f + ((size_t)bn * 528 + bz * 132) * 128 + 2 * jg;

  __shared__ float At[16][528];                 // 33.8 KB: whole K-slice

  {
    const int r = t >> 4, lane16 = t & 15;
    const float* hrow = h_ws + (size_t)(row0 + r) * CEMB + bz * 528;
    #pragma unroll
    for (int ii = 0; ii < 9; ++ii) {
      const int c4 = lane16 + ii * 16;
      if (c4 < 132) {
        *(float4*)&At[r][c4 * 4] = *(const float4*)&hrow[c4 * 4];
      }
    }
  }
  __syncthreads();

  float accx[4] = {0.f, 0.f, 0.f, 0.f};
  float accy[4] = {0.f, 0.f, 0.f, 0.f};
  #pragma unroll 4
  for (int cc = 0; cc < 132; ++cc) {
    const float4 wv0 = W4[(size_t)cc * 128];
    const float4 wv1 = W4[(size_t)cc * 128 + 1];
    #pragma unroll
    for (int r = 0; r < 4; ++r) {
      const float4 s = *(const float4*)&At[g * 4 + r][cc * 4];  // broadcast
      accx[r] = fma4(s, wv0, accx[r]);
      accy[r] = fma4(s, wv1, accy[r]);
    }
  }

  float* pb = part + ((size_t)bz * NROWS + row0) * 256 + bn * 128 + 2 * jg;
  #pragma unroll
  for (int r = 0; r < 4; ++r) {
    *(float2*)&pb[(size_t)(g * 4 + r) * 256] = make_float2(accx[r], accy[r]);
  }
}

// ---------------------------------------------------------------------------
// K_gcn: grid 32, block 256. Layer thread = (q = t>>6: 5 rows of 20-row
// padded state, jg = t&63: col-pair {2jg,2jg+1}, BOTH paths).
// Same 4 row-groups as r16 (512KB W L2/layer, unchanged) but HALF the
// ds_read_b128 count (640 vs 1280 wave-instrs/layer). 4-slot dist-3 ring
// (r18-proven spill-safe) hides W L2 latency at 4 waves.
// ---------------------------------------------------------------------------
__device__ __forceinline__ void layer256(
    const float (*S)[HID], const float4* __restrict__ W0,
    const float4* __restrict__ W1, float (*O0)[HID], float (*O1)[HID],
    int q, int jg) {
  const int r0 = q * 5;                 // rows r0..r0+4 (rows 17..19 pad)
  float a0x[5], a0y[5], a1x[5], a1y[5];
  #pragma unroll
  for (int r = 0; r < 5; ++r) { a0x[r]=0.f; a0y[r]=0.f; a1x[r]=0.f; a1y[r]=0.f; }

  // 4-slot ring (slot = cc % 4, static after full unroll), prefetch dist 3
  float4 w0a[4], w0b[4], w1a[4], w1b[4];
  #pragma unroll
  for (int u = 0; u < 3; ++u) {
    w0a[u] = W0[u * 128 + 2 * jg];
    w0b[u] = W0[u * 128 + 2 * jg + 1];
    w1a[u] = W1[u * 128 + 2 * jg];
    w1b[u] = W1[u * 128 + 2 * jg + 1];
  }
  #pragma unroll
  for (int cc = 0; cc < 32; ++cc) {
    if (cc < 29) {                       // prefetch chunk cc+3 (static guard)
      const int sp = (cc + 3) % 4;
      w0a[sp] = W0[(cc + 3) * 128 + 2 * jg];
      w0b[sp] = W0[(cc + 3) * 128 + 2 * jg + 1];
      w1a[sp] = W1[(cc + 3) * 128 + 2 * jg];
      w1b[sp] = W1[(cc + 3) * 128 + 2 * jg + 1];
    }
    const int sl = cc % 4;
    const float4 v0a = w0a[sl], v0b = w0b[sl], v1a = w1a[sl], v1b = w1b[sl];
    #pragma unroll
    for (int r = 0; r < 5; ++r) {
      const float4 s = *(const float4*)&S[r0 + r][cc * 4];  // wave-uniform bcast
      a0x[r] = fma4(s, v0a, a0x[r]);
      a0y[r] = fma4(s, v0b, a0y[r]);
      a1x[r] = fma4(s, v1a, a1x[r]);
      a1y[r] = fma4(s, v1b, a1y[r]);
    }
  }
  #pragma unroll
  for (int r = 0; r < 5; ++r) {
    *(float2*)&O0[r0 + r][2 * jg] = make_float2(a0x[r], a0y[r]);
    *(float2*)&O1[r0 + r][2 * jg] = make_float2(a1x[r], a1y[r]);
  }
}

// Sparse masked mix + BN + ReLU. thread = (half = t>>7: 9 rows, d = t&127).
template <int ADD>
__device__ __forceinline__ void mix_bn2(
    const float (*T0)[HID], const float (*T1)[HID], const float (*A)[KJ],
    float pb, float pg, float pt, float (*dst)[HID], int half, int d) {
  const float gsv = pg * 0.99999500003749969f;  // gamma * rsqrt(1+1e-5)
  #pragma unroll
  for (int k = 0; k < 9; ++k) {
    const int i = half * 9 + k;
    if (i < KJ) {
      float s = A[i][i] * T0[i][d];
      #pragma unroll
      for (int e = 0; e < 4; ++e) {
        const int jj = (int)c_nbr4[i][e];
        s = fmaf(A[i][jj], T1[jj][d], s);
      }
      const float v = fmaxf(fmaf(s + pb, gsv, pt), 0.f);
      if (ADD) dst[i][d] += v; else dst[i][d] = v;
    }
  }
}

__global__ __launch_bounds__(256) void k_gcn(
    const float* __restrict__ part,
    const float* __restrict__ Ei, const float* __restrict__ bi,
    const float* __restrict__ gi, const float* __restrict__ bti,
    const float* __restrict__ Wph, const float* __restrict__ bh,
    const float* __restrict__ Eh, const float* __restrict__ gh,
    const float* __restrict__ bth, const float* __restrict__ Wo,
    const float* __restrict__ bo, const float* __restrict__ Eo,
    float* __restrict__ out) {
  __shared__ float adjm[10][KJ][KJ];
  __shared__ float Hs[20][HID], Rs[20][HID], T0s[20][HID], T1s[20][HID];
  const int n = blockIdx.x, t = threadIdx.x;
  const int q = t >> 6, jg = t & 63;     // layer mapping (4 rowgroups x 64 pairs)
  const int half = t >> 7, d = t & 127;  // mix mapping

  const float ibb = bi[d], igg = gi[d], ibt = bti[d];

  // 0) adjacency softmax for all 10 gconvs (Ei, Eh[0..7], Eo)
  if (t < 170) {
    const int m = t / KJ, i = t % KJ;
    const float* Es = (m == 0) ? Ei : ((m <= 8) ? Eh + (size_t)(m - 1) * KJ * KJ : Eo);
    const unsigned msk = c_mask[i];
    float mx = -1e30f;
    #pragma unroll
    for (int jj = 0; jj < KJ; ++jj)
      if (msk & (1u << jj)) mx = fmaxf(mx, Es[i * KJ + jj]);
    float ev[KJ];
    float sum = 0.f;
    #pragma unroll
    for (int jj = 0; jj < KJ; ++jj) {
      const float e = (msk & (1u << jj)) ? expf(Es[i * KJ + jj] - mx) : 0.f;
      ev[jj] = e; sum += e;
    }
    const float inv = 1.f / sum;
    #pragma unroll
    for (int jj = 0; jj < KJ; ++jj) adjm[m][i][jj] = ev[jj] * inv;
  }
  // zero pad-rows 17..19 (3 rows x 128 = 384 slots)
  for (int idx = t; idx < 384; idx += 256) {
    Hs[17 + (idx >> 7)][idx & 127] = 0.f;
    Rs[17 + (idx >> 7)][idx & 127] = 0.f;
  }

  // 1) sum split-K partials of input gconv h0/h1
  {
    const float* p0 = part + (size_t)(n * KJ) * 256;
    for (int idx = t; idx < KJ * 256; idx += 256) {
      const int k = idx >> 8, jj = idx & 255;
      float v = 0.f;
      #pragma unroll
      for (int z = 0; z < SPLITK; ++z)
        v += p0[(size_t)z * NROWS * 256 + k * 256 + jj];
      if (jj < HID) T0s[k][jj] = v; else T1s[k][jj - HID] = v;
    }
  }
  __syncthreads();

  // 2) input mixing + BN + ReLU -> Hs
  mix_bn2<0>(T0s, T1s, adjm[0], ibb, igg, ibt, Hs, half, d);
  __syncthreads();

  // 3) 4 residual blocks x 2 gconvs (layer256 + 4-slot ring)
  const float4* Wp4 = (const float4*)Wph;
  for (int l = 0; l < 4; ++l) {
    const int iA = 2 * l, iB = 2 * l + 1;
    {
      const float pb = bh[iA * HID + d], pg = gh[iA * HID + d], pt = bth[iA * HID + d];
      layer256(Hs, Wp4 + (size_t)(iA * 2) * 4096, Wp4 + (size_t)(iA * 2 + 1) * 4096,
               T0s, T1s, q, jg);
      __syncthreads();
      mix_bn2<0>(T0s, T1s, adjm[1 + iA], pb, pg, pt, Rs, half, d);
      __syncthreads();
    }
    {
      const float pb = bh[iB * HID + d], pg = gh[iB * HID + d], pt = bth[iB * HID + d];
      layer256(Rs, Wp4 + (size_t)(iB * 2) * 4096, Wp4 + (size_t)(iB * 2 + 1) * 4096,
               T0s, T1s, q, jg);
      __syncthreads();
      mix_bn2<1>(T0s, T1s, adjm[1 + iB], pb, pg, pt, Hs, half, d);
      __syncthreads();
    }
  }

  // 4) output gconv (no BN/ReLU): 128 -> 3
  if (t < 102) {
    const int pp = t / 51, rem = t % 51, i = rem / 3, e = rem % 3;
    const float* Wp = Wo + pp * HID * 3 + e;
    float s = 0.f;
    #pragma unroll 4
    for (int c = 0; c < HID; ++c) s = fmaf(Hs[i][c], Wp[c * 3], s);
    if (pp == 0) T0s[i][e] = s; else T1s[i][e] = s;
  }
  __syncthreads();
  if (t < 51) {
    const int i = t / 3, e = t % 3;
    const float (*A)[KJ] = adjm[9];
    float s = bo[e];
    #pragma unroll
    for (int jj = 0; jj < KJ; ++jj) s = fmaf(A[i][jj], T1s[jj][e], s);
    s += A[i][i] * (T0s[i][e] - T1s[i][e]);
    out[(n * KJ + i) * 3 + e] = s;
  }
}

// ---------------------------------------------------------------------------
extern "C" void kernel_launch(void* const* d_in, const int* in_sizes, int n_in,
                              void* d_out, int out_size, void* d_ws, size_t ws_size,
                              hipStream_t stream) {
  const float* x       = (const float*)d_in[0];
  const float* heatmap = (const float*)d_in[1];
  const float* bbox    = (const float*)d_in[2];
  const float* pos_w   = (const float*)d_in[3];
  const float* pos_b   = (const float*)d_in[4];
  const float* Wi      = (const float*)d_in[5];
  const float* bi      = (const float*)d_in[6];
  const float* Ei      = (const float*)d_in[7];
  const float* gi      = (const float*)d_in[8];
  const float* bti     = (const float*)d_in[9];
  const float* Wh      = (const float*)d_in[10];
  const float* bh      = (const float*)d_in[11];
  const float* Eh      = (const float*)d_in[12];
  const float* gh      = (const float*)d_in[13];
  const float* bth     = (const float*)d_in[14];
  const float* Wo      = (const float*)d_in[15];
  const float* bo      = (const float*)d_in[16];
  const float* Eo      = (const float*)d_in[17];
  float* out = (float*)d_out;

  // ws layout (floats): h[544*2112] | part[4*544*256] | Wpi[540672] | Wph[262144]
  float* h_ws = (float*)d_ws;
  float* part = h_ws + (size_t)NROWS * CEMB;
  float* Wpi  = part + (size_t)SPLITK * NROWS * 256;
  float* Wph  = Wpi + (size_t)2 * CEMB * HID;

  k_front<<<NROWS + 528 + 256, 256, 0, stream>>>(
      heatmap, bbox, pos_w, pos_b, Wi, Wh, x, h_ws,
      (float4*)Wpi, (float4*)Wph);
  k_gemm_in<<<dim3(34, 2, SPLITK), 256, 0, stream>>>(Wpi, h_ws, part);
  k_gcn<<<NB, 256, 0, stream>>>(part, Ei, bi, gi, bti, Wph, bh, Eh, gh, bth,
                                Wo, bo, Eo, out);
}

// Round 21
// 122.158 us; speedup vs baseline: 1.3346x; 1.3346x over previous
//
#include <hip/hip_runtime.h>

// Problem constants (from reference)
#define NB    32
#define KJ    17
#define CIN   2048
#define HWSZ  4096     // H*W = 64*64
#define WDIM  64
#define CEMB  2112     // 64 + 2048
#define HID   128
#define NROWS (NB*KJ)  // 544
#define SPLITK 4

// Skeleton adjacency mask (H36M edges + diagonal), row i -> bitmask over j
__device__ __constant__ unsigned c_mask[KJ] = {
  0x00093u, 0x00007u, 0x0000Eu, 0x0000Cu, 0x00031u, 0x00070u, 0x00060u,
  0x00181u, 0x04B80u, 0x00700u, 0x00600u, 0x01900u, 0x03800u, 0x03000u,
  0x0C100u, 0x1C000u, 0x18000u
};

// Sparse neighbor table (excl. diagonal), padded to 4 with non-edge indices
// (A[i][pad] == 0 after masked softmax, so pads contribute exactly 0).
__device__ __constant__ unsigned char c_nbr4[KJ][4] = {
  {1,4,7,2},{0,2,3,3},{1,3,0,0},{2,0,0,0},{0,5,1,1},{4,6,0,0},{5,0,0,0},
  {0,8,1,1},{7,9,11,14},{8,10,0,0},{9,0,0,0},{8,12,0,0},{11,13,0,0},
  {12,0,0,0},{8,15,0,0},{14,16,0,0},{15,0,0,0}
};

// function, not macro: macro param named `w` collides with `.w` member
__device__ __forceinline__ float fma4(const float4 s, const float4 wv, float a) {
  return fmaf(s.x, wv.x, fmaf(s.y, wv.y, fmaf(s.z, wv.z, fmaf(s.w, wv.w, a))));
}

// ---------------------------------------------------------------------------
// K_front: blocks 0..543: heatmap argmax + posemb + OWN-ROW feature gather.
//          blocks 544..1327: weight repack (gather-read, coalesced write).
// ---------------------------------------------------------------------------
__global__ __launch_bounds__(256) void k_front(
    const float* __restrict__ heatmap, const float* __restrict__ bbox,
    const float* __restrict__ pos_w, const float* __restrict__ pos_b,
    const float* __restrict__ Wi, const float* __restrict__ Wh,
    const float* __restrict__ x, float* __restrict__ h_ws,
    float4* __restrict__ Wpi4, float4* __restrict__ Wph4) {
  const int blk = blockIdx.x;
  const int t = threadIdx.x;

  if (blk >= NROWS) {                    // ---- packing blocks ----
    const int pb = blk - NROWS;
    if (pb < 528) {                      // Wpi: 135168 float4
      const int idx4 = pb * 256 + t;
      const int d = idx4 & 127, rest = idx4 >> 7;
      const int c4 = rest % 528, p = rest / 528;
      const float* src = Wi + ((size_t)(p * CEMB + c4 * 4)) * HID + d;
      Wpi4[((size_t)p * 528 + c4) * 128 + d] =
          make_float4(src[0], src[HID], src[2 * HID], src[3 * HID]);
    } else {                             // Wph: 65536 float4
      const int idx4 = (pb - 528) * 256 + t;
      const int d = idx4 & 127, rest = idx4 >> 7;
      const int c4 = rest & 31, lp = rest >> 5;
      const float* src = Wh + ((size_t)(lp * HID + c4 * 4)) * HID + d;
      Wph4[((size_t)lp * 32 + c4) * 128 + d] =
          make_float4(src[0], src[HID], src[2 * HID], src[3 * HID]);
    }
    return;
  }

  // ---- per-(n,k) blocks ----
  const int b = blk;                     // n*17 + k
  const int n = b / KJ;
  __shared__ float svals[256];
  __shared__ int   sidx[256];

  const float4* hm4 = (const float4*)(heatmap + (size_t)b * HWSZ);
  float best = -1e30f; int bidx = 0;
  #pragma unroll
  for (int k = 0; k < 4; ++k) {
    const int vi = k * 256 + t;
    const float4 v = hm4[vi];
    const int base = vi * 4;
    if (v.x > best) { best = v.x; bidx = base;     }
    if (v.y > best) { best = v.y; bidx = base + 1; }
    if (v.z > best) { best = v.z; bidx = base + 2; }
    if (v.w > best) { best = v.w; bidx = base + 3; }
  }
  svals[t] = best; sidx[t] = bidx;
  __syncthreads();
  for (int s = 128; s > 0; s >>= 1) {
    if (t < s) {
      const float v2 = svals[t + s]; const int i2 = sidx[t + s];
      if (v2 > svals[t] || (v2 == svals[t] && i2 < sidx[t])) {
        svals[t] = v2; sidx[t] = i2;
      }
    }
    __syncthreads();
  }
  const int loc = sidx[0];               // valid in all threads

  if (t < 64) {
    const float kx = (float)(loc & (WDIM - 1));
    const float ky = (float)(loc >> 6);
    float in6[6];
    in6[0] = kx * (2.0f / 64.0f) - 1.0f;
    in6[1] = ky * (2.0f / 64.0f) - 1.0f;
    in6[2] = bbox[n * 4 + 0] * (2.0f / 1920.0f) - 1.0f;
    in6[3] = bbox[n * 4 + 1] * (2.0f / 1080.0f) - 1.0f;
    in6[4] = bbox[n * 4 + 2] * (1.0f / 1920.0f);
    in6[5] = bbox[n * 4 + 3] * (1.0f / 1080.0f);
    float acc = pos_b[t];
    #pragma unroll
    for (int c = 0; c < 6; ++c) acc = fmaf(in6[c], pos_w[c * 64 + t], acc);
    h_ws[(size_t)b * CEMB + t] = acc;
  }

  // own-row scattered gather: 8 channels/thread, independent loads
  const float* xn = x + (size_t)n * CIN * HWSZ + loc;
  float* hrow = h_ws + (size_t)b * CEMB + 64;
  #pragma unroll
  for (int k = 0; k < 8; ++k) {
    const int c = k * 256 + t;
    hrow[c] = xn[(size_t)c * HWSZ];
  }
}

// ---------------------------------------------------------------------------
// K_gemm V3: input GEMM  C[544][256] = h[544][2112] @ [Wi0|Wi1], split-K=4
// grid (34, 2, 4), block 256 = 4 rowgroups x 64 colpairs. Each thread:
// 4 rows x 2 adjacent cols -> 8 fma4 per 4 ds_read_b128; W pairwise-contig.
// ---------------------------------------------------------------------------
__global__ __launch_bounds__(256) void k_gemm_in(
    const float* __restrict__ Wpi_f, const float* __restrict__ h_ws,
    float* __restrict__ part) {
  const int bm = blockIdx.x, bn = blockIdx.y, bz = blockIdx.z;
  const int t = threadIdx.x;
  const int jg = t & 63, g = t >> 6;            // colpair, row group (4 rows)
  const int row0 = bm * 16;
  const float4* W4 = (const float4*)Wpi_f + ((size_t)bn * 528 + bz * 132) * 128 + 2 * jg;

  __shared__ float At[16][528];                 // 33.8 KB: whole K-slice

  {
    const int r = t >> 4, lane16 = t & 15;
    const float* hrow = h_ws + (size_t)(row0 + r) * CEMB + bz * 528;
    #pragma unroll
    for (int ii = 0; ii < 9; ++ii) {
      const int c4 = lane16 + ii * 16;
      if (c4 < 132) {
        *(float4*)&At[r][c4 * 4] = *(const float4*)&hrow[c4 * 4];
      }
    }
  }
  __syncthreads();

  float accx[4] = {0.f, 0.f, 0.f, 0.f};
  float accy[4] = {0.f, 0.f, 0.f, 0.f};
  #pragma unroll 4
  for (int cc = 0; cc < 132; ++cc) {
    const float4 wv0 = W4[(size_t)cc * 128];
    const float4 wv1 = W4[(size_t)cc * 128 + 1];
    #pragma unroll
    for (int r = 0; r < 4; ++r) {
      const float4 s = *(const float4*)&At[g * 4 + r][cc * 4];  // broadcast
      accx[r] = fma4(s, wv0, accx[r]);
      accy[r] = fma4(s, wv1, accy[r]);
    }
  }

  float* pb = part + ((size_t)bz * NROWS + row0) * 256 + bn * 128 + 2 * jg;
  #pragma unroll
  for (int r = 0; r < 4; ++r) {
    *(float2*)&pb[(size_t)(g * 4 + r) * 256] = make_float2(accx[r], accy[r]);
  }
}

// ---------------------------------------------------------------------------
// K_gcn: grid 32, block 512: q = t>>7 (5 rows), j = t&127.  (r16 structure —
// measured optimum of the {threads, row-groups, ring} design space.)
// layer4s: static 4-slot weight ring per path (32 VGPR total, no movs).
// mix: sparse neighbor table (<=4 edges) instead of dense 17-column loop.
// ---------------------------------------------------------------------------
__device__ __forceinline__ void layer4s(
    const float (*S)[HID], const float4* __restrict__ W0,
    const float4* __restrict__ W1, float (*O0)[HID], float (*O1)[HID],
    int q, int j) {
  const int r0 = q * 5;                 // rows r0..r0+4 (rows 17..19 are pad)
  float a0[5] = {0.f, 0.f, 0.f, 0.f, 0.f};
  float a1[5] = {0.f, 0.f, 0.f, 0.f, 0.f};
  float4 w0s[4], w1s[4];                // slot = cc % 4, static after unroll

  #pragma unroll
  for (int u = 0; u < 3; ++u) {
    w0s[u] = W0[u * 128 + j];
    w1s[u] = W1[u * 128 + j];
  }
  #pragma unroll
  for (int cc = 0; cc < 32; ++cc) {
    if (cc < 29) {                      // prefetch chunk cc+3 (static guard)
      w0s[(cc + 3) % 4] = W0[(cc + 3) * 128 + j];
      w1s[(cc + 3) % 4] = W1[(cc + 3) * 128 + j];
    }
    const float4 wv0 = w0s[cc % 4];
    const float4 wv1 = w1s[cc % 4];
    #pragma unroll
    for (int r = 0; r < 5; ++r) {
      const float4 s = *(const float4*)&S[r0 + r][cc * 4];  // wave-uniform bcast
      a0[r] = fma4(s, wv0, a0[r]);
      a1[r] = fma4(s, wv1, a1[r]);
    }
  }
  #pragma unroll
  for (int r = 0; r < 5; ++r) { O0[r0 + r][j] = a0[r]; O1[r0 + r][j] = a1[r]; }
}

// Sparse masked mix + BN + ReLU (<=4 neighbors + diagonal).
template <int ADD>
__device__ __forceinline__ void mix_bn2(
    const float (*T0)[HID], const float (*T1)[HID], const float (*A)[KJ],
    float pb, float pg, float pt, float (*dst)[HID], int q, int d) {
  const float gsv = pg * 0.99999500003749969f;  // gamma * rsqrt(1+1e-5)
  for (int i = q; i < KJ; i += 4) {
    float s = A[i][i] * T0[i][d];
    #pragma unroll
    for (int e = 0; e < 4; ++e) {
      const int jj = (int)c_nbr4[i][e];
      s = fmaf(A[i][jj], T1[jj][d], s);
    }
    const float v = fmaxf(fmaf(s + pb, gsv, pt), 0.f);
    if (ADD) dst[i][d] += v; else dst[i][d] = v;
  }
}

__global__ __launch_bounds__(512) void k_gcn(
    const float* __restrict__ part,
    const float* __restrict__ Ei, const float* __restrict__ bi,
    const float* __restrict__ gi, const float* __restrict__ bti,
    const float* __restrict__ Wph, const float* __restrict__ bh,
    const float* __restrict__ Eh, const float* __restrict__ gh,
    const float* __restrict__ bth, const float* __restrict__ Wo,
    const float* __restrict__ bo, const float* __restrict__ Eo,
    float* __restrict__ out) {
  __shared__ float adjm[10][KJ][KJ];
  __shared__ float Hs[20][HID], Rs[20][HID], T0s[20][HID], T1s[20][HID];
  const int n = blockIdx.x, t = threadIdx.x;
  const int q = t >> 7, j = t & 127;

  const float ibb = bi[j], igg = gi[j], ibt = bti[j];

  // 0) adjacency softmax for all 10 gconvs (Ei, Eh[0..7], Eo)
  if (t < 170) {
    const int m = t / KJ, i = t % KJ;
    const float* Es = (m == 0) ? Ei : ((m <= 8) ? Eh + (size_t)(m - 1) * KJ * KJ : Eo);
    const unsigned msk = c_mask[i];
    float mx = -1e30f;
    #pragma unroll
    for (int jj = 0; jj < KJ; ++jj)
      if (msk & (1u << jj)) mx = fmaxf(mx, Es[i * KJ + jj]);
    float ev[KJ];
    float sum = 0.f;
    #pragma unroll
    for (int jj = 0; jj < KJ; ++jj) {
      const float e = (msk & (1u << jj)) ? expf(Es[i * KJ + jj] - mx) : 0.f;
      ev[jj] = e; sum += e;
    }
    const float inv = 1.f / sum;
    #pragma unroll
    for (int jj = 0; jj < KJ; ++jj) adjm[m][i][jj] = ev[jj] * inv;
  }
  // zero pad-rows 17..19
  if (t < 384) { Hs[17 + (t >> 7)][t & 127] = 0.f; Rs[17 + (t >> 7)][t & 127] = 0.f; }

  // 1) sum split-K partials of input gconv h0/h1
  {
    const float* p0 = part + (size_t)(n * KJ) * 256;
    for (int idx = t; idx < KJ * 256; idx += 512) {
      const int k = idx >> 8, jj = idx & 255;
      float v = 0.f;
      #pragma unroll
      for (int z = 0; z < SPLITK; ++z)
        v += p0[(size_t)z * NROWS * 256 + k * 256 + jj];
      if (jj < HID) T0s[k][jj] = v; else T1s[k][jj - HID] = v;
    }
  }
  __syncthreads();

  // 2) input mixing + BN + ReLU -> Hs
  mix_bn2<0>(T0s, T1s, adjm[0], ibb, igg, ibt, Hs, q, j);
  __syncthreads();

  // 3) 4 residual blocks x 2 gconvs, packed weights (static 4-slot ring)
  const float4* Wp4 = (const float4*)Wph;
  for (int l = 0; l < 4; ++l) {
    const int iA = 2 * l, iB = 2 * l + 1;
    {
      const float pb = bh[iA * HID + j], pg = gh[iA * HID + j], pt = bth[iA * HID + j];
      layer4s(Hs, Wp4 + (size_t)(iA * 2) * 4096, Wp4 + (size_t)(iA * 2 + 1) * 4096,
              T0s, T1s, q, j);
      __syncthreads();
      mix_bn2<0>(T0s, T1s, adjm[1 + iA], pb, pg, pt, Rs, q, j);
      __syncthreads();
    }
    {
      const float pb = bh[iB * HID + j], pg = gh[iB * HID + j], pt = bth[iB * HID + j];
      layer4s(Rs, Wp4 + (size_t)(iB * 2) * 4096, Wp4 + (size_t)(iB * 2 + 1) * 4096,
              T0s, T1s, q, j);
      __syncthreads();
      mix_bn2<1>(T0s, T1s, adjm[1 + iB], pb, pg, pt, Hs, q, j);
      __syncthreads();
    }
  }

  // 4) output gconv (no BN/ReLU): 128 -> 3
  if (t < 102) {
    const int pp = t / 51, rem = t % 51, i = rem / 3, e = rem % 3;
    const float* Wp = Wo + pp * HID * 3 + e;
    float s = 0.f;
    #pragma unroll 4
    for (int c = 0; c < HID; ++c) s = fmaf(Hs[i][c], Wp[c * 3], s);
    if (pp == 0) T0s[i][e] = s; else T1s[i][e] = s;
  }
  __syncthreads();
  if (t < 51) {
    const int i = t / 3, e = t % 3;
    const float (*A)[KJ] = adjm[9];
    float s = bo[e];
    #pragma unroll
    for (int jj = 0; jj < KJ; ++jj) s = fmaf(A[i][jj], T1s[jj][e], s);
    s += A[i][i] * (T0s[i][e] - T1s[i][e]);
    out[(n * KJ + i) * 3 + e] = s;
  }
}

// ---------------------------------------------------------------------------
extern "C" void kernel_launch(void* const* d_in, const int* in_sizes, int n_in,
                              void* d_out, int out_size, void* d_ws, size_t ws_size,
                              hipStream_t stream) {
  const float* x       = (const float*)d_in[0];
  const float* heatmap = (const float*)d_in[1];
  const float* bbox    = (const float*)d_in[2];
  const float* pos_w   = (const float*)d_in[3];
  const float* pos_b   = (const float*)d_in[4];
  const float* Wi      = (const float*)d_in[5];
  const float* bi      = (const float*)d_in[6];
  const float* Ei      = (const float*)d_in[7];
  const float* gi      = (const float*)d_in[8];
  const float* bti     = (const float*)d_in[9];
  const float* Wh      = (const float*)d_in[10];
  const float* bh      = (const float*)d_in[11];
  const float* Eh      = (const float*)d_in[12];
  const float* gh      = (const float*)d_in[13];
  const float* bth     = (const float*)d_in[14];
  const float* Wo      = (const float*)d_in[15];
  const float* bo      = (const float*)d_in[16];
  const float* Eo      = (const float*)d_in[17];
  float* out = (float*)d_out;

  // ws layout (floats): h[544*2112] | part[4*544*256] | Wpi[540672] | Wph[262144]
  float* h_ws = (float*)d_ws;
  float* part = h_ws + (size_t)NROWS * CEMB;
  float* Wpi  = part + (size_t)SPLITK * NROWS * 256;
  float* Wph  = Wpi + (size_t)2 * CEMB * HID;

  k_front<<<NROWS + 528 + 256, 256, 0, stream>>>(
      heatmap, bbox, pos_w, pos_b, Wi, Wh, x, h_ws,
      (float4*)Wpi, (float4*)Wph);
  k_gemm_in<<<dim3(34, 2, SPLITK), 256, 0, stream>>>(Wpi, h_ws, part);
  k_gcn<<<NB, 512, 0, stream>>>(part, Ei, bi, gi, bti, Wph, bh, Eh, gh, bth,
                                Wo, bo, Eo, out);
}